// Round 12
// baseline (290.396 us; speedup 1.0000x reference)
//
#include <hip/hip_runtime.h>
#include <hip/hip_bf16.h>

#define Bv 1024
#define Nv 64
#define Ev 1024
#define Dv 128
#define Hv 4
#define Lv 2
#define Kv 5
#define PAD 136   // bf16 LDS row stride; 272 B = 16B multiple -> b128-loadable rows

typedef __hip_bfloat16 bf16;
typedef __attribute__((ext_vector_type(8))) short bf16x8_t;  // 8 bf16 in 4 VGPRs
typedef __attribute__((ext_vector_type(4))) float f32x4_t;   // MFMA accum / b128 f32 loads
typedef __attribute__((ext_vector_type(2))) float f32x2_t;

__device__ __forceinline__ float b2f(bf16 v) { return __bfloat162float(v); }
__device__ __forceinline__ bf16  f2b(float v) { return __float2bfloat16(v); }

// Packed MFMA B-fragment weights (bf16 hi/lo planes) in device-global memory.
__device__ bf16 g_pWl[(size_t)Lv * 2 * Dv * Dv];   // [L][2 planes][128*128]
__device__ bf16 g_pWr[(size_t)Lv * 2 * Dv * Dv];   // [L][2 planes][128*128]
__device__ bf16 g_pW1[(size_t)2 * 2 * Dv * Dv];    // [2 planes][256*128]
__device__ float g_K[Lv * Hv];                     // 0.2 * sum_c att[l,h,c]*We[l,h,c]
// CSR-sorted packed edge table: u32 = s | t<<6 | bf16(ea)<<16. Independent loads.
__device__ unsigned int g_etab[Ev];
__device__ int          g_off[Nv + 1];             // per-dst bucket offsets

__device__ __forceinline__ f32x2_t unpack2v(unsigned int u) {
    union { unsigned int u; float f; } a, b;
    a.u = u << 16;
    b.u = u & 0xffff0000u;
    return (f32x2_t){a.f, b.f};
}

__device__ __forceinline__ unsigned int pack2v(f32x2_t v) {
    union { bf16 b; unsigned short u; } lo, hi;
    lo.b = f2b(v.x); hi.b = f2b(v.y);
    return (unsigned int)lo.u | ((unsigned int)hi.u << 16);
}

__device__ __forceinline__ bf16x8_t load8(const bf16* p, int elem) {
    return *(const bf16x8_t*)(p + elem);
}
union b8u { bf16x8_t v; unsigned int u[4]; };

// ---------------- weight packing into MFMA B-fragment order ----------------
__device__ void pack_mat(const float* __restrict__ W, bf16* __restrict__ out,
                         int K, int tid, int nth)
{
    const int total = K * 128;
    for (int e = tid; e < total; e += nth) {
        int f    = e >> 9;
        int rem  = e & 511;
        int lane = rem >> 3;
        int i    = rem & 7;
        int kk   = f >> 3;
        int nt   = f & 7;
        int col  = nt * 16 + (lane & 15);
        int k    = kk * 32 + (lane >> 4) * 8 + i;
        float w  = W[k * 128 + col];
        bf16 hi  = f2b(w);
        out[e]         = hi;
        out[total + e] = f2b(w - b2f(hi));
    }
}

// ---------------- prep: block 0 = CSR sort; blocks 1.. = weight packing ----------------
__global__ void prep(const int* __restrict__ edge_index, const float* __restrict__ edge_attr,
                     const float* __restrict__ Wl, const float* __restrict__ Wr,
                     const float* __restrict__ W1, const float* __restrict__ We,
                     const float* __restrict__ att)
{
    const int bid = blockIdx.x;
    if (bid == 0) {
        __shared__ int cnt[Nv];
        int tid = threadIdx.x;
        if (tid < Nv) cnt[tid] = 0;
        __syncthreads();
        for (int e = tid; e < Ev; e += blockDim.x)
            atomicAdd(&cnt[edge_index[Ev + e]], 1);
        __syncthreads();
        if (tid == 0) {
            int s = 0;
            for (int t = 0; t < Nv; ++t) { int c = cnt[t]; g_off[t] = s; cnt[t] = s; s += c; }
            g_off[Nv] = s;
        }
        __syncthreads();
        for (int e = tid; e < Ev; e += blockDim.x) {
            int s = edge_index[e];
            int d = edge_index[Ev + e];
            int pos = atomicAdd(&cnt[d], 1);
            union { bf16 b; unsigned short u; } cv;
            cv.b = f2b(edge_attr[e]);
            g_etab[pos] = (unsigned int)(s | (d << 6)) | ((unsigned int)cv.u << 16);
        }
        return;
    }
    const int nth = (gridDim.x - 1) * 256;
    const int tid = (bid - 1) * 256 + threadIdx.x;
    for (int l = 0; l < Lv; ++l) {
        pack_mat(Wl + (size_t)l * Dv * Dv, g_pWl + (size_t)l * 2 * Dv * Dv, Dv, tid, nth);
        pack_mat(Wr + (size_t)l * Dv * Dv, g_pWr + (size_t)l * 2 * Dv * Dv, Dv, tid, nth);
    }
    pack_mat(W1, g_pW1, 2 * Dv, tid, nth);
    if (bid == 1 && threadIdx.x < Lv * Hv) {
        int l = threadIdx.x / Hv, h = threadIdx.x % Hv;
        float k = 0.f;
        for (int c = 0; c < 32; ++c)
            k += att[l * Dv + h * 32 + c] * We[l * Dv + h * 32 + c];
        g_K[threadIdx.x] = 0.2f * k;
    }
}

// ---------------- fused kernel: 2 batch elements per block (512 thr / 8 waves) ----------------
// launch_bounds (512, 2): NEVER tighten — r3: spill catastrophe; r7: WRONG RESULTS.
// Occupancy pinned at 1 block/CU (r8/r9: neither VGPR<=128 nor LDS<=63.5KB restored
// 2 blocks) -> LDS is FREE up to 160KB. So: process TWO batch elements per block
// (same graph/weights across batch!): topology + weight loads amortize x2, the
// latency-exposed serial loops (gather/logits) get 2 independent ILP streams,
// barrier fixed cost halves. Per-element math order identical -> bit-exact vs r11.
__global__ __launch_bounds__(512, 2)
void gat_fused(const int* __restrict__ x,
               const float* __restrict__ attr_emb,
               const float* __restrict__ opt_emb, const float* __restrict__ prior,
               const float* __restrict__ bl, const float* __restrict__ br,
               const float* __restrict__ conv_bias, const float* __restrict__ ln_g,
               const float* __restrict__ ln_b,
               const float* __restrict__ b1, const float* __restrict__ W2,
               const float* __restrict__ b2,
               const float* __restrict__ We, const float* __restrict__ att,
               float* __restrict__ out_fscale, float* __restrict__ out_rel,
               float* __restrict__ out_hatT)
{
    const int b0  = blockIdx.x * 2;
    const int tid = threadIdx.x;

    __shared__ __align__(16) bf16 hs [2][Nv * PAD];
    __shared__ __align__(16) bf16 xls[2][Nv * PAD];
    __shared__ __align__(16) bf16 xrs[2][Nv * PAD];
    __shared__ __align__(16) bf16 alphas[2][Ev * Hv];
    __shared__ __align__(16) float red [2][Nv * 8];
    __shared__ __align__(16) float red2[2][Nv * 8];
    __shared__ __align__(16) float watt[256];       // [h][cpair]{we0,we1,at0,at1}
    __shared__ __align__(16) float w2col[Dv];
    __shared__ float relbuf[2][Nv];

    const int my_t = tid & 63;
    const int beg  = g_off[my_t];
    const int end  = g_off[my_t + 1];

    // ---- T0 -> hs ----
    for (int idx = tid; idx < Nv * Dv; idx += 512) {
        int n = idx >> 7, d = idx & 127;
        float ae = attr_emb[n * Dv + d];
        float pr = prior[n];
        #pragma unroll
        for (int el = 0; el < 2; ++el) {
            float t0 = (ae + opt_emb[(n * Kv + x[(b0 + el) * Nv + n]) * Dv + d]) * pr;
            hs[el][n * PAD + d] = f2b(t0);
        }
    }

    for (int l = 0; l < Lv; ++l) {
        if (tid < 256) {
            int h = tid >> 6, cp = (tid >> 2) & 15, e = tid & 3;
            int c = cp * 2 + (e & 1);
            watt[tid] = (e < 2) ? We[l * Dv + h * 32 + c] : att[l * Dv + h * 32 + c];
        }
        __syncthreads();

        // ---- GEMM via MFMA: [xl | xr] = h @ [Wl | Wr] + bias (both elements) ----
        // B-fragments loaded ONCE per kk, used by both elements.
        {
            const int w = tid >> 6, lane = tid & 63;
            const int row16 = lane & 15, kg = lane >> 4;
            const bf16* pB = (w < 4) ? (g_pWl + (size_t)l * 2 * Dv * Dv)
                                     : (g_pWr + (size_t)l * 2 * Dv * Dv);
            const int wc = (w & 3) * 32;
            const float* bias = (w < 4) ? (bl + l * Dv) : (br + l * Dv);

            #pragma unroll
            for (int nt = 0; nt < 2; ++nt) {
                f32x4_t acc[2][4];
                #pragma unroll
                for (int el = 0; el < 2; ++el)
                    #pragma unroll
                    for (int mt = 0; mt < 4; ++mt)
                        acc[el][mt] = (f32x4_t){0.f, 0.f, 0.f, 0.f};

                #pragma unroll
                for (int kk = 0; kk < 4; ++kk) {
                    const int kb = kk * 32 + kg * 8;
                    const int f = kk * 8 + (w & 3) * 2 + nt;
                    bf16x8_t bh  = *(const bf16x8_t*)&pB[(size_t)(f * 64 + lane) * 8];
                    bf16x8_t blo = *(const bf16x8_t*)&pB[Dv * Dv + (size_t)(f * 64 + lane) * 8];
                    #pragma unroll
                    for (int mt = 0; mt < 4; ++mt) {
                        #pragma unroll
                        for (int el = 0; el < 2; ++el) {
                            bf16x8_t a = load8(hs[el], (mt * 16 + row16) * PAD + kb);
                            acc[el][mt] = __builtin_amdgcn_mfma_f32_16x16x32_bf16(a, bh,  acc[el][mt], 0, 0, 0);
                            acc[el][mt] = __builtin_amdgcn_mfma_f32_16x16x32_bf16(a, blo, acc[el][mt], 0, 0, 0);
                        }
                    }
                }
                const int col = wc + nt * 16 + row16;
                const float bv = bias[col];
                #pragma unroll
                for (int el = 0; el < 2; ++el) {
                    bf16* dst = (w < 4) ? xls[el] : xrs[el];
                    #pragma unroll
                    for (int mt = 0; mt < 4; ++mt) {
                        #pragma unroll
                        for (int r = 0; r < 4; ++r) {
                            const int row = mt * 16 + kg * 4 + r;
                            dst[row * PAD + col] = f2b(acc[el][mt][r] + bv);
                        }
                    }
                }
            }
        }
        __syncthreads();

        // ---- per (n,h,half): linear att-dot of xl -> red (dotR cancels in softmax) ----
        {
            const int t = tid & 63, h = (tid >> 6) & 3, half = tid >> 8;
            const int ch0 = h * 32 + half * 16;
            #pragma unroll
            for (int el = 0; el < 2; ++el) {
                b8u a0, a1;
                a0.v = load8(xls[el], t * PAD + ch0);
                a1.v = load8(xls[el], t * PAD + ch0 + 8);
                f32x2_t dl2 = {0.f, 0.f};
                #pragma unroll
                for (int j = 0; j < 4; ++j) {
                    f32x2_t at2 = *(const f32x2_t*)&watt[h * 64 + (half * 8 + j) * 4 + 2];
                    dl2 += at2 * unpack2v(a0.u[j]);
                }
                #pragma unroll
                for (int j = 0; j < 4; ++j) {
                    f32x2_t at2 = *(const f32x2_t*)&watt[h * 64 + (half * 8 + 4 + j) * 4 + 2];
                    dl2 += at2 * unpack2v(a1.u[j]);
                }
                red[el][t * 8 + h * 2 + half] = dl2.x + dl2.y;
            }
        }
        __syncthreads();

        // ---- per-edge per-head logits, q-outer/edge-inner, both elements ----
        // alpha = 0.2*dotL[s] + 0.2*K*ea + 0.8*sum_c att_c*max(v_c,0)
        {
            const int h = (tid >> 6) & 3, half = tid >> 8, lane = tid & 63;
            const float k02 = g_K[l * Hv + h];
            const f32x2_t zero2 = {0.f, 0.f};
            unsigned int ets[8];
            #pragma unroll
            for (int e = 0; e < 8; ++e)
                ets[e] = g_etab[(half * 8 + e) * 64 + lane];
            f32x2_t acc[2][8];
            #pragma unroll
            for (int el = 0; el < 2; ++el)
                #pragma unroll
                for (int e = 0; e < 8; ++e) acc[el][e] = (f32x2_t){0.f, 0.f};

            #pragma unroll
            for (int q = 0; q < 4; ++q) {
                f32x4_t wa[4];
                #pragma unroll
                for (int j = 0; j < 4; ++j)
                    wa[j] = *(const f32x4_t*)&watt[h * 64 + (q * 4 + j) * 4];
                #pragma unroll
                for (int e = 0; e < 8; ++e) {
                    int s = ets[e] & 63, t = (ets[e] >> 6) & 63;
                    union { unsigned int u; float f; } ec; ec.u = ets[e] & 0xffff0000u;
                    f32x2_t ea2 = {ec.f, ec.f};
                    #pragma unroll
                    for (int el = 0; el < 2; ++el) {
                        b8u xl, xr;
                        xl.v = load8(xls[el], s * PAD + h * 32 + q * 8);
                        xr.v = load8(xrs[el], t * PAD + h * 32 + q * 8);
                        #pragma unroll
                        for (int j = 0; j < 4; ++j) {
                            f32x2_t xl2 = unpack2v(xl.u[j]);
                            f32x2_t xr2 = unpack2v(xr.u[j]);
                            f32x2_t we2 = {wa[j].x, wa[j].y};
                            f32x2_t at2 = {wa[j].z, wa[j].w};
                            f32x2_t v   = xl2 + xr2 + ea2 * we2;
                            acc[el][e] += at2 * __builtin_elementwise_max(v, zero2);
                        }
                    }
                }
            }
            #pragma unroll
            for (int e = 0; e < 8; ++e) {
                int s = ets[e] & 63;
                union { unsigned int u; float f; } ec; ec.u = ets[e] & 0xffff0000u;
                #pragma unroll
                for (int el = 0; el < 2; ++el) {
                    float dL = red[el][s * 8 + h * 2] + red[el][s * 8 + h * 2 + 1];
                    float alpha = 0.2f * dL + k02 * ec.f + 0.8f * (acc[el][e].x + acc[el][e].y);
                    alphas[el][((half * 8 + e) * 64 + lane) * Hv + h] = f2b(alpha);
                }
            }
        }
        __syncthreads();

        // ---- per (dst, head, half): softmax-fused gather + LN + ELU + residual ----
        {
            const int t = my_t, h = (tid >> 6) & 3, half = tid >> 8;
            const int ch0 = h * 32 + half * 16;
            float mx[2] = {-3e38f, -3e38f};
            for (int idx = beg; idx < end; ++idx) {
                #pragma unroll
                for (int el = 0; el < 2; ++el)
                    mx[el] = fmaxf(mx[el], b2f(alphas[el][idx * Hv + h]));
            }
            f32x2_t acc2[2][8];
            #pragma unroll
            for (int el = 0; el < 2; ++el)
                #pragma unroll
                for (int j = 0; j < 8; ++j) acc2[el][j] = (f32x2_t){0.f, 0.f};
            float den[2] = {0.f, 0.f};
            for (int idx = beg; idx < end; ++idx) {
                int s = (int)(g_etab[idx] & 63u);
                #pragma unroll
                for (int el = 0; el < 2; ++el) {
                    float ex = expf(b2f(alphas[el][idx * Hv + h]) - mx[el]);
                    den[el] += ex;
                    f32x2_t ex2 = {ex, ex};
                    b8u m0, m1;
                    m0.v = load8(xls[el], s * PAD + ch0);
                    m1.v = load8(xls[el], s * PAD + ch0 + 8);
                    #pragma unroll
                    for (int j = 0; j < 4; ++j)
                        acc2[el][j] += ex2 * unpack2v(m0.u[j]);
                    #pragma unroll
                    for (int j = 0; j < 4; ++j)
                        acc2[el][4 + j] += ex2 * unpack2v(m1.u[j]);
                }
            }
            f32x2_t id2[2], sum2[2], sq2[2];
            #pragma unroll
            for (int el = 0; el < 2; ++el) {
                float inv_den = (end > beg) ? 1.f / den[el] : 0.f;
                id2[el] = (f32x2_t){inv_den, inv_den};
                sum2[el] = (f32x2_t){0.f, 0.f};
                sq2[el]  = (f32x2_t){0.f, 0.f};
            }
            #pragma unroll
            for (int j = 0; j < 8; ++j) {
                f32x2_t cb = *(const f32x2_t*)&conv_bias[l * Dv + ch0 + 2 * j];
                #pragma unroll
                for (int el = 0; el < 2; ++el) {
                    f32x2_t g = acc2[el][j] * id2[el] + cb;
                    acc2[el][j] = g;
                    sum2[el] += g; sq2[el] += g * g;
                }
            }
            #pragma unroll
            for (int el = 0; el < 2; ++el) {
                red [el][t * 8 + h * 2 + half] = sum2[el].x + sum2[el].y;
                red2[el][t * 8 + h * 2 + half] = sq2[el].x + sq2[el].y;
            }
            __syncthreads();
            f32x2_t mu2[2], rs2[2];
            #pragma unroll
            for (int el = 0; el < 2; ++el) {
                float mu = 0.f, ms = 0.f;
                #pragma unroll
                for (int j = 0; j < 8; ++j) { mu += red[el][t * 8 + j]; ms += red2[el][t * 8 + j]; }
                mu *= (1.f / 128.f); ms *= (1.f / 128.f);
                float rstd = rsqrtf(ms - mu * mu + 1e-5f);
                mu2[el] = (f32x2_t){mu, mu};
                rs2[el] = (f32x2_t){rstd, rstd};
            }
            #pragma unroll
            for (int j = 0; j < 8; ++j) {
                f32x2_t lg = *(const f32x2_t*)&ln_g[l * Dv + ch0 + 2 * j];
                f32x2_t lb = *(const f32x2_t*)&ln_b[l * Dv + ch0 + 2 * j];
                #pragma unroll
                for (int el = 0; el < 2; ++el) {
                    f32x2_t g = (acc2[el][j] - mu2[el]) * rs2[el] * lg + lb;
                    g.x = g.x > 0.f ? g.x : (expf(g.x) - 1.f);
                    g.y = g.y > 0.f ? g.y : (expf(g.y) - 1.f);
                    unsigned int* hp = (unsigned int*)&hs[el][t * PAD + ch0 + 2 * j];
                    f32x2_t hv = unpack2v(*hp) + g;      // residual
                    *hp = pack2v(hv);
                }
            }
        }
        __syncthreads();
    }

    // ---- hat_T (f32 out); T0 -> xrs; preload W2 ----
    if (tid < Dv) w2col[tid] = W2[tid];
    for (int idx = tid; idx < Nv * Dv; idx += 512) {
        int n = idx >> 7, d = idx & 127;
        float ae = attr_emb[n * Dv + d];
        float pr = prior[n];
        #pragma unroll
        for (int el = 0; el < 2; ++el) {
            int bb = b0 + el;
            float t0 = (ae + opt_emb[(n * Kv + x[bb * Nv + n]) * Dv + d]) * pr;
            xrs[el][n * PAD + d] = f2b(t0);
            size_t rb = ((size_t)(bb * Nv + n)) * (2 * Dv);
            out_hatT[rb + d]      = t0;
            out_hatT[rb + Dv + d] = b2f(hs[el][n * PAD + d]);
        }
    }
    __syncthreads();

    // ---- hidden = relu([T0,h] @ W1 + b1) -> xls  (MFMA, K=256, both elements) ----
    {
        const int w = tid >> 6, lane = tid & 63;
        const int row16 = lane & 15, kg = lane >> 4;
        f32x4_t acc[2][4];
        #pragma unroll
        for (int el = 0; el < 2; ++el)
            #pragma unroll
            for (int mt = 0; mt < 4; ++mt)
                acc[el][mt] = (f32x4_t){0.f, 0.f, 0.f, 0.f};

        #pragma unroll
        for (int kk = 0; kk < 8; ++kk) {
            const int kb = (kk & 3) * 32 + kg * 8;
            const int f = kk * 8 + w;
            bf16x8_t bh  = *(const bf16x8_t*)&g_pW1[(size_t)(f * 64 + lane) * 8];
            bf16x8_t blo = *(const bf16x8_t*)&g_pW1[(size_t)2 * Dv * Dv + (size_t)(f * 64 + lane) * 8];
            #pragma unroll
            for (int mt = 0; mt < 4; ++mt) {
                #pragma unroll
                for (int el = 0; el < 2; ++el) {
                    const bf16* asrc = (kk < 4) ? xrs[el] : hs[el];
                    bf16x8_t a = load8(asrc, (mt * 16 + row16) * PAD + kb);
                    acc[el][mt] = __builtin_amdgcn_mfma_f32_16x16x32_bf16(a, bh,  acc[el][mt], 0, 0, 0);
                    acc[el][mt] = __builtin_amdgcn_mfma_f32_16x16x32_bf16(a, blo, acc[el][mt], 0, 0, 0);
                }
            }
        }
        const int col = w * 16 + row16;
        const float bv = b1[col];
        #pragma unroll
        for (int el = 0; el < 2; ++el) {
            #pragma unroll
            for (int mt = 0; mt < 4; ++mt) {
                #pragma unroll
                for (int r = 0; r < 4; ++r) {
                    const int row = mt * 16 + kg * 4 + r;
                    float v = acc[el][mt][r] + bv;
                    xls[el][row * PAD + col] = f2b(v > 0.f ? v : 0.f);
                }
            }
        }
    }
    __syncthreads();

    // ---- rel = sigmoid(hidden @ W2 + b2) (f32 out) ----
    {
        const int t = tid & 63, h = (tid >> 6) & 3, half = tid >> 8;
        const int ch0 = h * 32 + half * 16;
        #pragma unroll
        for (int el = 0; el < 2; ++el) {
            b8u h0, h1;
            h0.v = load8(xls[el], t * PAD + ch0);
            h1.v = load8(xls[el], t * PAD + ch0 + 8);
            f32x2_t s2 = {0.f, 0.f};
            #pragma unroll
            for (int j = 0; j < 4; ++j)
                s2 += unpack2v(h0.u[j]) * *(const f32x2_t*)&w2col[ch0 + 2 * j];
            #pragma unroll
            for (int j = 0; j < 4; ++j)
                s2 += unpack2v(h1.u[j]) * *(const f32x2_t*)&w2col[ch0 + 8 + 2 * j];
            red[el][t * 8 + h * 2 + half] = s2.x + s2.y;
        }
        __syncthreads();
        if (h == 0 && half == 0) {
            #pragma unroll
            for (int el = 0; el < 2; ++el) {
                float z = b2[0];
                #pragma unroll
                for (int j = 0; j < 8; ++j) z += red[el][t * 8 + j];
                float r = 1.f / (1.f + expf(-z));
                relbuf[el][t] = r;
                out_rel[(b0 + el) * Nv + t] = r;
            }
        }
    }
    __syncthreads();

    // ---- f_scale (f32 out) ----
    if (tid < Dv) {
        #pragma unroll
        for (int el = 0; el < 2; ++el) {
            float num = 0.f, den = 0.f;
            for (int n = 0; n < Nv; ++n) {
                float r = relbuf[el][n];
                num += b2f(hs[el][n * PAD + tid]) * r;
                den += r;
            }
            out_fscale[(b0 + el) * Dv + tid] = num / (den + 1e-8f);
        }
    }
}

extern "C" void kernel_launch(void* const* d_in, const int* in_sizes, int n_in,
                              void* d_out, int out_size, void* d_ws, size_t ws_size,
                              hipStream_t stream)
{
    const int*   x          = (const int*)  d_in[0];
    const int*   edge_index = (const int*)  d_in[1];
    const float* edge_attr  = (const float*)d_in[2];
    const float* attr_emb   = (const float*)d_in[3];
    const float* opt_emb    = (const float*)d_in[4];
    const float* prior      = (const float*)d_in[5];
    const float* Wl         = (const float*)d_in[6];
    const float* bl         = (const float*)d_in[7];
    const float* Wr         = (const float*)d_in[8];
    const float* br         = (const float*)d_in[9];
    const float* We         = (const float*)d_in[10];
    const float* att        = (const float*)d_in[11];
    const float* conv_bias  = (const float*)d_in[12];
    const float* ln_g       = (const float*)d_in[13];
    const float* ln_b       = (const float*)d_in[14];
    const float* W1         = (const float*)d_in[15];
    const float* b1         = (const float*)d_in[16];
    const float* W2         = (const float*)d_in[17];
    const float* b2         = (const float*)d_in[18];

    float* out        = (float*)d_out;
    float* out_fscale = out;                                      // B*D
    float* out_rel    = out + (size_t)Bv * Dv;                    // B*N
    float* out_hatT   = out + (size_t)Bv * Dv + (size_t)Bv * Nv;  // B*N*2D

    prep<<<129, 256, 0, stream>>>(edge_index, edge_attr, Wl, Wr, W1, We, att);
    gat_fused<<<Bv / 2, 512, 0, stream>>>(x, attr_emb, opt_emb,
                                          prior, bl, br, conv_bias,
                                          ln_g, ln_b, b1, W2, b2, We, att,
                                          out_fscale, out_rel, out_hatT);
}

// Round 13
// 266.401 us; speedup vs baseline: 1.0901x; 1.0901x over previous
//
#include <hip/hip_runtime.h>
#include <hip/hip_bf16.h>

#define Bv 1024
#define Nv 64
#define Ev 1024
#define Dv 128
#define Hv 4
#define Lv 2
#define Kv 5
#define PAD  136  // bf16 LDS row stride (hs, t0b): 272 B, 16B multiple
#define PADF 132  // f32 LDS row stride (xls, xrs): 528 B, 16B multiple, 4-bank row advance

typedef __hip_bfloat16 bf16;
typedef __attribute__((ext_vector_type(8))) short bf16x8_t;  // 8 bf16 in 4 VGPRs
typedef __attribute__((ext_vector_type(4))) float f32x4_t;   // MFMA accum / b128 f32 loads
typedef __attribute__((ext_vector_type(2))) float f32x2_t;   // packed dual-f32

__device__ __forceinline__ float b2f(bf16 v) { return __bfloat162float(v); }
__device__ __forceinline__ bf16  f2b(float v) { return __float2bfloat16(v); }

// Packed MFMA B-fragment weights (bf16 hi/lo planes) in device-global memory.
__device__ bf16 g_pWl[(size_t)Lv * 2 * Dv * Dv];   // [L][2 planes][128*128]
__device__ bf16 g_pWr[(size_t)Lv * 2 * Dv * Dv];   // [L][2 planes][128*128]
__device__ bf16 g_pW1[(size_t)2 * 2 * Dv * Dv];    // [2 planes][256*128]
__device__ float g_K[Lv * Hv];                     // 0.2 * sum_c att[l,h,c]*We[l,h,c]
// CSR-sorted packed edge table: u32 = s | t<<6 | bf16(ea)<<16. Independent loads.
__device__ unsigned int g_etab[Ev];
__device__ int          g_off[Nv + 1];             // per-dst bucket offsets

__device__ __forceinline__ unsigned int pack2v(f32x2_t v) {
    union { bf16 b; unsigned short u; } lo, hi;
    lo.b = f2b(v.x); hi.b = f2b(v.y);
    return (unsigned int)lo.u | ((unsigned int)hi.u << 16);
}
__device__ __forceinline__ f32x2_t unpack2v(unsigned int u) {
    union { unsigned int u; float f; } a, b;
    a.u = u << 16;
    b.u = u & 0xffff0000u;
    return (f32x2_t){a.f, b.f};
}

__device__ __forceinline__ bf16x8_t load8(const bf16* p, int elem) {
    return *(const bf16x8_t*)(p + elem);
}
__device__ __forceinline__ f32x4_t load4f(const float* p, int elem) {
    return *(const f32x4_t*)(p + elem);
}
__device__ __forceinline__ f32x2_t lo2(f32x4_t v) { return (f32x2_t){v.x, v.y}; }
__device__ __forceinline__ f32x2_t hi2(f32x4_t v) { return (f32x2_t){v.z, v.w}; }

// ---------------- weight packing into MFMA B-fragment order ----------------
__device__ void pack_mat(const float* __restrict__ W, bf16* __restrict__ out,
                         int K, int tid, int nth)
{
    const int total = K * 128;
    for (int e = tid; e < total; e += nth) {
        int f    = e >> 9;
        int rem  = e & 511;
        int lane = rem >> 3;
        int i    = rem & 7;
        int kk   = f >> 3;
        int nt   = f & 7;
        int col  = nt * 16 + (lane & 15);
        int k    = kk * 32 + (lane >> 4) * 8 + i;
        float w  = W[k * 128 + col];
        bf16 hi  = f2b(w);
        out[e]         = hi;
        out[total + e] = f2b(w - b2f(hi));
    }
}

// ---------------- prep: block 0 = CSR sort; blocks 1.. = weight packing ----------------
__global__ void prep(const int* __restrict__ edge_index, const float* __restrict__ edge_attr,
                     const float* __restrict__ Wl, const float* __restrict__ Wr,
                     const float* __restrict__ W1, const float* __restrict__ We,
                     const float* __restrict__ att)
{
    const int bid = blockIdx.x;
    if (bid == 0) {
        __shared__ int cnt[Nv];
        int tid = threadIdx.x;
        if (tid < Nv) cnt[tid] = 0;
        __syncthreads();
        for (int e = tid; e < Ev; e += blockDim.x)
            atomicAdd(&cnt[edge_index[Ev + e]], 1);
        __syncthreads();
        if (tid == 0) {
            int s = 0;
            for (int t = 0; t < Nv; ++t) { int c = cnt[t]; g_off[t] = s; cnt[t] = s; s += c; }
            g_off[Nv] = s;
        }
        __syncthreads();
        for (int e = tid; e < Ev; e += blockDim.x) {
            int s = edge_index[e];
            int d = edge_index[Ev + e];
            int pos = atomicAdd(&cnt[d], 1);
            union { bf16 b; unsigned short u; } cv;
            cv.b = f2b(edge_attr[e]);
            g_etab[pos] = (unsigned int)(s | (d << 6)) | ((unsigned int)cv.u << 16);
        }
        return;
    }
    const int nth = (gridDim.x - 1) * 256;
    const int tid = (bid - 1) * 256 + threadIdx.x;
    for (int l = 0; l < Lv; ++l) {
        pack_mat(Wl + (size_t)l * Dv * Dv, g_pWl + (size_t)l * 2 * Dv * Dv, Dv, tid, nth);
        pack_mat(Wr + (size_t)l * Dv * Dv, g_pWr + (size_t)l * 2 * Dv * Dv, Dv, tid, nth);
    }
    pack_mat(W1, g_pW1, 2 * Dv, tid, nth);
    if (bid == 1 && threadIdx.x < Lv * Hv) {
        int l = threadIdx.x / Hv, h = threadIdx.x % Hv;
        float k = 0.f;
        for (int c = 0; c < 32; ++c)
            k += att[l * Dv + h * 32 + c] * We[l * Dv + h * 32 + c];
        g_K[threadIdx.x] = 0.2f * k;
    }
}

// ---------------- fused per-batch-element kernel (512 thr / 8 waves) ----------------
// launch_bounds (512, 2): NEVER tighten — r3: spill catastrophe; r7: WRONG RESULTS.
// r12: 2 elems/block -> 128 VGPR + scratch spill (WRITE 66->134MB), neutral. Reverted.
// Occupancy pinned at 1 block/CU (r8/r9) -> LDS free to 160KB. This version stores
// activations xls/xrs (VALU-only consumers) as F32: eliminates the bf16 unpack
// shift/mask pairs that dominated VALU issue in logits/gather/att-dot/rel.
// hs stays bf16 (MFMA A-operand + residual); T0 for the MLP goes to bf16 t0b.
__global__ __launch_bounds__(512, 2)
void gat_fused(const int* __restrict__ x,
               const float* __restrict__ attr_emb,
               const float* __restrict__ opt_emb, const float* __restrict__ prior,
               const float* __restrict__ bl, const float* __restrict__ br,
               const float* __restrict__ conv_bias, const float* __restrict__ ln_g,
               const float* __restrict__ ln_b,
               const float* __restrict__ b1, const float* __restrict__ W2,
               const float* __restrict__ b2,
               const float* __restrict__ We, const float* __restrict__ att,
               float* __restrict__ out_fscale, float* __restrict__ out_rel,
               float* __restrict__ out_hatT)
{
    const int b = blockIdx.x;
    const int tid = threadIdx.x;

    __shared__ __align__(16) bf16  hs [Nv * PAD];
    __shared__ __align__(16) bf16  t0b[Nv * PAD];     // bf16 T0 copy for MLP A-operand
    __shared__ __align__(16) float xls[Nv * PADF];    // f32 activations (VALU phases)
    __shared__ __align__(16) float xrs[Nv * PADF];
    __shared__ __align__(16) bf16 alphas[Ev * Hv];    // sorted-position-major
    __shared__ __align__(16) float red [Nv * 8];
    __shared__ __align__(16) float red2[Nv * 8];
    __shared__ __align__(16) float watt[256];         // [h][cpair]{we0,we1,at0,at1}
    __shared__ __align__(16) float w2col[Dv];
    __shared__ float relbuf[Nv];

    const int my_t = tid & 63;
    const int beg  = g_off[my_t];
    const int end  = g_off[my_t + 1];

    // ---- T0 -> hs ----
    for (int idx = tid; idx < Nv * Dv; idx += 512) {
        int n = idx >> 7, d = idx & 127;
        float t0 = (attr_emb[n * Dv + d] + opt_emb[(n * Kv + x[b * Nv + n]) * Dv + d])
                   * prior[n];
        hs[n * PAD + d] = f2b(t0);
    }

    for (int l = 0; l < Lv; ++l) {
        if (tid < 256) {
            int h = tid >> 6, cp = (tid >> 2) & 15, e = tid & 3;
            int c = cp * 2 + (e & 1);
            watt[tid] = (e < 2) ? We[l * Dv + h * 32 + c] : att[l * Dv + h * 32 + c];
        }
        __syncthreads();

        // ---- GEMM via MFMA: [xl | xr] = h @ [Wl | Wr] + bias -> F32 LDS ----
        // nt-outer 2-pass, acc[4]; bit-exact accumulation order.
        {
            const int w = tid >> 6, lane = tid & 63;
            const int row16 = lane & 15, kg = lane >> 4;
            const bf16* pB = (w < 4) ? (g_pWl + (size_t)l * 2 * Dv * Dv)
                                     : (g_pWr + (size_t)l * 2 * Dv * Dv);
            const int wc = (w & 3) * 32;
            float* dst = (w < 4) ? xls : xrs;
            const float* bias = (w < 4) ? (bl + l * Dv) : (br + l * Dv);

            #pragma unroll
            for (int nt = 0; nt < 2; ++nt) {
                f32x4_t acc[4];
                #pragma unroll
                for (int mt = 0; mt < 4; ++mt)
                    acc[mt] = (f32x4_t){0.f, 0.f, 0.f, 0.f};

                #pragma unroll
                for (int kk = 0; kk < 4; ++kk) {
                    const int kb = kk * 32 + kg * 8;
                    const int f = kk * 8 + (w & 3) * 2 + nt;
                    bf16x8_t bh  = *(const bf16x8_t*)&pB[(size_t)(f * 64 + lane) * 8];
                    bf16x8_t blo = *(const bf16x8_t*)&pB[Dv * Dv + (size_t)(f * 64 + lane) * 8];
                    #pragma unroll
                    for (int mt = 0; mt < 4; ++mt) {
                        bf16x8_t a = load8(hs, (mt * 16 + row16) * PAD + kb);
                        acc[mt] = __builtin_amdgcn_mfma_f32_16x16x32_bf16(a, bh,  acc[mt], 0, 0, 0);
                        acc[mt] = __builtin_amdgcn_mfma_f32_16x16x32_bf16(a, blo, acc[mt], 0, 0, 0);
                    }
                }
                const int col = wc + nt * 16 + row16;
                const float bv = bias[col];
                #pragma unroll
                for (int mt = 0; mt < 4; ++mt) {
                    #pragma unroll
                    for (int r = 0; r < 4; ++r) {
                        const int row = mt * 16 + kg * 4 + r;
                        dst[row * PADF + col] = acc[mt][r] + bv;   // f32, no f2b
                    }
                }
            }
        }
        __syncthreads();

        // ---- per (n,h,half): linear att-dot of xl -> red (dotR cancels in softmax) ----
        {
            const int t = tid & 63, h = (tid >> 6) & 3, half = tid >> 8;
            const int ch0 = h * 32 + half * 16;
            f32x4_t a0 = load4f(xls, t * PADF + ch0);
            f32x4_t a1 = load4f(xls, t * PADF + ch0 + 4);
            f32x4_t a2 = load4f(xls, t * PADF + ch0 + 8);
            f32x4_t a3 = load4f(xls, t * PADF + ch0 + 12);
            const float* wb = &watt[h * 64 + half * 32];
            f32x2_t dl2 = {0.f, 0.f};
            dl2 += *(const f32x2_t*)(wb + 0*4 + 2) * lo2(a0);
            dl2 += *(const f32x2_t*)(wb + 1*4 + 2) * hi2(a0);
            dl2 += *(const f32x2_t*)(wb + 2*4 + 2) * lo2(a1);
            dl2 += *(const f32x2_t*)(wb + 3*4 + 2) * hi2(a1);
            dl2 += *(const f32x2_t*)(wb + 4*4 + 2) * lo2(a2);
            dl2 += *(const f32x2_t*)(wb + 5*4 + 2) * hi2(a2);
            dl2 += *(const f32x2_t*)(wb + 6*4 + 2) * lo2(a3);
            dl2 += *(const f32x2_t*)(wb + 7*4 + 2) * hi2(a3);
            red[t * 8 + h * 2 + half] = dl2.x + dl2.y;
        }
        __syncthreads();

        // ---- per-edge per-head logits, q-outer/edge-inner, f32 b128 loads ----
        // alpha = 0.2*dotL[s] + 0.2*K*ea + 0.8*sum_c att_c*max(v_c,0)
        {
            const int h = (tid >> 6) & 3, half = tid >> 8, lane = tid & 63;
            const float k02 = g_K[l * Hv + h];
            const f32x2_t zero2 = {0.f, 0.f};
            unsigned int ets[8];
            #pragma unroll
            for (int e = 0; e < 8; ++e)
                ets[e] = g_etab[(half * 8 + e) * 64 + lane];
            f32x2_t acc[8];
            #pragma unroll
            for (int e = 0; e < 8; ++e) acc[e] = (f32x2_t){0.f, 0.f};

            #pragma unroll
            for (int q = 0; q < 4; ++q) {
                f32x4_t wa[4];
                #pragma unroll
                for (int j = 0; j < 4; ++j)
                    wa[j] = *(const f32x4_t*)&watt[h * 64 + (q * 4 + j) * 4];
                #pragma unroll
                for (int e = 0; e < 8; ++e) {
                    int s = ets[e] & 63, t = (ets[e] >> 6) & 63;
                    f32x4_t xl0 = load4f(xls, s * PADF + h * 32 + q * 8);
                    f32x4_t xl1 = load4f(xls, s * PADF + h * 32 + q * 8 + 4);
                    f32x4_t xr0 = load4f(xrs, t * PADF + h * 32 + q * 8);
                    f32x4_t xr1 = load4f(xrs, t * PADF + h * 32 + q * 8 + 4);
                    union { unsigned int u; float f; } ec; ec.u = ets[e] & 0xffff0000u;
                    f32x2_t ea2 = {ec.f, ec.f};
                    f32x2_t v, we2, at2;
                    we2 = (f32x2_t){wa[0].x, wa[0].y}; at2 = (f32x2_t){wa[0].z, wa[0].w};
                    v = lo2(xl0) + lo2(xr0) + ea2 * we2;
                    acc[e] += at2 * __builtin_elementwise_max(v, zero2);
                    we2 = (f32x2_t){wa[1].x, wa[1].y}; at2 = (f32x2_t){wa[1].z, wa[1].w};
                    v = hi2(xl0) + hi2(xr0) + ea2 * we2;
                    acc[e] += at2 * __builtin_elementwise_max(v, zero2);
                    we2 = (f32x2_t){wa[2].x, wa[2].y}; at2 = (f32x2_t){wa[2].z, wa[2].w};
                    v = lo2(xl1) + lo2(xr1) + ea2 * we2;
                    acc[e] += at2 * __builtin_elementwise_max(v, zero2);
                    we2 = (f32x2_t){wa[3].x, wa[3].y}; at2 = (f32x2_t){wa[3].z, wa[3].w};
                    v = hi2(xl1) + hi2(xr1) + ea2 * we2;
                    acc[e] += at2 * __builtin_elementwise_max(v, zero2);
                }
            }
            #pragma unroll
            for (int e = 0; e < 8; ++e) {
                int s = ets[e] & 63;
                union { unsigned int u; float f; } ec; ec.u = ets[e] & 0xffff0000u;
                float dL = red[s * 8 + h * 2] + red[s * 8 + h * 2 + 1];
                float alpha = 0.2f * dL + k02 * ec.f + 0.8f * (acc[e].x + acc[e].y);
                alphas[((half * 8 + e) * 64 + lane) * Hv + h] = f2b(alpha);
            }
        }
        __syncthreads();

        // ---- per (dst, head, half): softmax-fused gather + LN + ELU + residual ----
        {
            const int t = my_t, h = (tid >> 6) & 3, half = tid >> 8;
            const int ch0 = h * 32 + half * 16;
            float mx = -3e38f;
            for (int idx = beg; idx < end; ++idx)
                mx = fmaxf(mx, b2f(alphas[idx * Hv + h]));
            f32x2_t acc2[8];
            #pragma unroll
            for (int j = 0; j < 8; ++j) acc2[j] = (f32x2_t){0.f, 0.f};
            float den = 0.f;
            for (int idx = beg; idx < end; ++idx) {
                int s = (int)(g_etab[idx] & 63u);
                float ex = expf(b2f(alphas[idx * Hv + h]) - mx);
                den += ex;
                f32x2_t ex2 = {ex, ex};
                f32x4_t m0 = load4f(xls, s * PADF + ch0);
                f32x4_t m1 = load4f(xls, s * PADF + ch0 + 4);
                f32x4_t m2 = load4f(xls, s * PADF + ch0 + 8);
                f32x4_t m3 = load4f(xls, s * PADF + ch0 + 12);
                acc2[0] += ex2 * lo2(m0); acc2[1] += ex2 * hi2(m0);
                acc2[2] += ex2 * lo2(m1); acc2[3] += ex2 * hi2(m1);
                acc2[4] += ex2 * lo2(m2); acc2[5] += ex2 * hi2(m2);
                acc2[6] += ex2 * lo2(m3); acc2[7] += ex2 * hi2(m3);
            }
            float inv_den = (end > beg) ? 1.f / den : 0.f;
            f32x2_t id2 = {inv_den, inv_den};
            f32x2_t sum2 = {0.f, 0.f}, sq2 = {0.f, 0.f};
            #pragma unroll
            for (int j = 0; j < 8; ++j) {
                f32x2_t cb = *(const f32x2_t*)&conv_bias[l * Dv + ch0 + 2 * j];
                f32x2_t g  = acc2[j] * id2 + cb;
                acc2[j] = g;
                sum2 += g; sq2 += g * g;
            }
            red [t * 8 + h * 2 + half] = sum2.x + sum2.y;
            red2[t * 8 + h * 2 + half] = sq2.x + sq2.y;
            __syncthreads();
            float mu = 0.f, ms = 0.f;
            #pragma unroll
            for (int j = 0; j < 8; ++j) { mu += red[t * 8 + j]; ms += red2[t * 8 + j]; }
            mu *= (1.f / 128.f); ms *= (1.f / 128.f);
            float rstd = rsqrtf(ms - mu * mu + 1e-5f);
            f32x2_t mu2 = {mu, mu}, rs2 = {rstd, rstd};
            #pragma unroll
            for (int j = 0; j < 8; ++j) {
                f32x2_t lg = *(const f32x2_t*)&ln_g[l * Dv + ch0 + 2 * j];
                f32x2_t lb = *(const f32x2_t*)&ln_b[l * Dv + ch0 + 2 * j];
                f32x2_t g  = (acc2[j] - mu2) * rs2 * lg + lb;
                g.x = g.x > 0.f ? g.x : (expf(g.x) - 1.f);
                g.y = g.y > 0.f ? g.y : (expf(g.y) - 1.f);
                unsigned int* hp = (unsigned int*)&hs[t * PAD + ch0 + 2 * j];
                f32x2_t hv = unpack2v(*hp) + g;      // residual
                *hp = pack2v(hv);
            }
        }
        __syncthreads();
    }

    // ---- hat_T (f32 out); T0 -> t0b (bf16 for MLP); preload W2 ----
    if (tid < Dv) w2col[tid] = W2[tid];
    for (int idx = tid; idx < Nv * Dv; idx += 512) {
        int n = idx >> 7, d = idx & 127;
        float t0 = (attr_emb[n * Dv + d] + opt_emb[(n * Kv + x[b * Nv + n]) * Dv + d])
                   * prior[n];
        t0b[n * PAD + d] = f2b(t0);
        size_t rb = ((size_t)(b * Nv + n)) * (2 * Dv);
        out_hatT[rb + d]      = t0;
        out_hatT[rb + Dv + d] = b2f(hs[n * PAD + d]);
    }
    __syncthreads();

    // ---- hidden = relu([T0,h] @ W1 + b1) -> xls (f32)  (MFMA, K=256) ----
    {
        const int w = tid >> 6, lane = tid & 63;
        const int row16 = lane & 15, kg = lane >> 4;
        f32x4_t acc[4];
        #pragma unroll
        for (int mt = 0; mt < 4; ++mt)
            acc[mt] = (f32x4_t){0.f, 0.f, 0.f, 0.f};

        #pragma unroll
        for (int kk = 0; kk < 8; ++kk) {
            const bf16* asrc = (kk < 4) ? t0b : hs;   // T0 then h
            const int kb = (kk & 3) * 32 + kg * 8;
            const int f = kk * 8 + w;
            bf16x8_t bh  = *(const bf16x8_t*)&g_pW1[(size_t)(f * 64 + lane) * 8];
            bf16x8_t blo = *(const bf16x8_t*)&g_pW1[(size_t)2 * Dv * Dv + (size_t)(f * 64 + lane) * 8];
            #pragma unroll
            for (int mt = 0; mt < 4; ++mt) {
                bf16x8_t a = load8(asrc, (mt * 16 + row16) * PAD + kb);
                acc[mt] = __builtin_amdgcn_mfma_f32_16x16x32_bf16(a, bh,  acc[mt], 0, 0, 0);
                acc[mt] = __builtin_amdgcn_mfma_f32_16x16x32_bf16(a, blo, acc[mt], 0, 0, 0);
            }
        }
        const int col = w * 16 + row16;
        const float bv = b1[col];
        #pragma unroll
        for (int mt = 0; mt < 4; ++mt) {
            #pragma unroll
            for (int r = 0; r < 4; ++r) {
                const int row = mt * 16 + kg * 4 + r;
                float v = acc[mt][r] + bv;
                xls[row * PADF + col] = v > 0.f ? v : 0.f;   // f32
            }
        }
    }
    __syncthreads();

    // ---- rel = sigmoid(hidden @ W2 + b2) (f32 out) ----
    {
        const int t = tid & 63, h = (tid >> 6) & 3, half = tid >> 8;
        const int ch0 = h * 32 + half * 16;
        f32x4_t h0 = load4f(xls, t * PADF + ch0);
        f32x4_t h1 = load4f(xls, t * PADF + ch0 + 4);
        f32x4_t h2 = load4f(xls, t * PADF + ch0 + 8);
        f32x4_t h3 = load4f(xls, t * PADF + ch0 + 12);
        f32x2_t s2 = {0.f, 0.f};
        s2 += lo2(h0) * *(const f32x2_t*)&w2col[ch0 + 0];
        s2 += hi2(h0) * *(const f32x2_t*)&w2col[ch0 + 2];
        s2 += lo2(h1) * *(const f32x2_t*)&w2col[ch0 + 4];
        s2 += hi2(h1) * *(const f32x2_t*)&w2col[ch0 + 6];
        s2 += lo2(h2) * *(const f32x2_t*)&w2col[ch0 + 8];
        s2 += hi2(h2) * *(const f32x2_t*)&w2col[ch0 + 10];
        s2 += lo2(h3) * *(const f32x2_t*)&w2col[ch0 + 12];
        s2 += hi2(h3) * *(const f32x2_t*)&w2col[ch0 + 14];
        red[t * 8 + h * 2 + half] = s2.x + s2.y;
        __syncthreads();
        if (h == 0 && half == 0) {
            float z = b2[0];
            #pragma unroll
            for (int j = 0; j < 8; ++j) z += red[t * 8 + j];
            float r = 1.f / (1.f + expf(-z));
            relbuf[t] = r;
            out_rel[b * Nv + t] = r;
        }
    }
    __syncthreads();

    // ---- f_scale (f32 out) ----
    if (tid < Dv) {
        float num = 0.f, den = 0.f;
        for (int n = 0; n < Nv; ++n) {
            float r = relbuf[n];
            num += b2f(hs[n * PAD + tid]) * r;
            den += r;
        }
        out_fscale[b * Dv + tid] = num / (den + 1e-8f);
    }
}

extern "C" void kernel_launch(void* const* d_in, const int* in_sizes, int n_in,
                              void* d_out, int out_size, void* d_ws, size_t ws_size,
                              hipStream_t stream)
{
    const int*   x          = (const int*)  d_in[0];
    const int*   edge_index = (const int*)  d_in[1];
    const float* edge_attr  = (const float*)d_in[2];
    const float* attr_emb   = (const float*)d_in[3];
    const float* opt_emb    = (const float*)d_in[4];
    const float* prior      = (const float*)d_in[5];
    const float* Wl         = (const float*)d_in[6];
    const float* bl         = (const float*)d_in[7];
    const float* Wr         = (const float*)d_in[8];
    const float* br         = (const float*)d_in[9];
    const float* We         = (const float*)d_in[10];
    const float* att        = (const float*)d_in[11];
    const float* conv_bias  = (const float*)d_in[12];
    const float* ln_g       = (const float*)d_in[13];
    const float* ln_b       = (const float*)d_in[14];
    const float* W1         = (const float*)d_in[15];
    const float* b1         = (const float*)d_in[16];
    const float* W2         = (const float*)d_in[17];
    const float* b2         = (const float*)d_in[18];

    float* out        = (float*)d_out;
    float* out_fscale = out;                                      // B*D
    float* out_rel    = out + (size_t)Bv * Dv;                    // B*N
    float* out_hatT   = out + (size_t)Bv * Dv + (size_t)Bv * Nv;  // B*N*2D

    prep<<<129, 256, 0, stream>>>(edge_index, edge_attr, Wl, Wr, W1, We, att);
    gat_fused<<<Bv, 512, 0, stream>>>(x, attr_emb, opt_emb,
                                      prior, bl, br, conv_bias,
                                      ln_g, ln_b, b1, W2, b2, We, att,
                                      out_fscale, out_rel, out_hatT);
}